// Round 14
// baseline (372.900 us; speedup 1.0000x reference)
//
#include <hip/hip_runtime.h>
#include <hip/hip_cooperative_groups.h>

namespace cg = cooperative_groups;

// N=100000, E=6400000. NB=782 buckets x NPB=128 nodes. TILE=25600 -> T=250.
constexpr int TILE  = 25600;      // edges per tile (unified path; 250 tiles)
constexpr int TPB   = 512;
constexpr int GRID  = 256;        // cooperative grid (1 block/CU)
constexpr int NPB   = 128;
constexpr int NBMAX = 1024;
constexpr int MAXBE = 10240;
constexpr int EPTH  = MAXBE / TPB;     // 20
constexpr int I4PT  = (TILE / 4 + TPB - 1) / TPB;  // 13
// fallback tile geometry (R12)
constexpr int FTILE = 16384;
constexpr int FEPT  = FTILE / TPB;     // 32

__device__ __forceinline__ int sw(int j)  { return j ^ (((j >> 7) & 7) << 2); }
__device__ __forceinline__ int sw4(int j) { return j ^ ((j >> 5) & 7); }

// ================= unified cooperative kernel =================

struct SP {
    int h[NBMAX];
    int lofs[NBMAX];
    int startb[NBMAX];
    unsigned int sorted[TILE];   // 100 KB
};
struct SA {
    int c[NPB];
    int lofs[NPB];
};
struct SB {
    int lsrc[MAXBE];             // 40 KB
    float sW1[64], sb1[16], sW2[32];
};
union USm { SP p; SA a; SB b; };

__global__ __launch_bounds__(TPB, 2) void k_uni(const int* __restrict__ src,
                                                const int* __restrict__ dst, int E,
                                                int* __restrict__ cursor,
                                                unsigned int* __restrict__ spack,
                                                const float* __restrict__ x,
                                                const float* __restrict__ W1,
                                                const float* __restrict__ b1,
                                                const float* __restrict__ W2,
                                                const float* __restrict__ b2,
                                                float* __restrict__ wx,
                                                float* __restrict__ wt,
                                                int* __restrict__ offn,
                                                int* __restrict__ degn,
                                                int* __restrict__ csr,
                                                float* __restrict__ out, int N) {
    __shared__ USm sm;
    cg::grid_group grid = cg::this_grid();
    int tid = threadIdx.x;
    const int NB = (N + NPB - 1) / NPB;
    const int T  = (E + TILE - 1) / TILE;

    // ---------------- phase P: partition (one tile per block) ----------------
    for (int t = blockIdx.x; t < T; t += gridDim.x) {
        for (int j = tid; j < NB; j += TPB) sm.p.h[j] = 0;
        __syncthreads();

        const int4* dv = reinterpret_cast<const int4*>(dst);
        const int4* sv = reinterpret_cast<const int4*>(src);
        int base4 = t * (TILE / 4);
        int lim4 = (t * TILE + TILE) / 4;

        unsigned short rr[I4PT * 4];

        // pass A: LDS histogram + per-edge rank (rank in regs)
#pragma unroll
        for (int k = 0; k < I4PT; ++k) {
            int i4 = base4 + k * TPB + tid;
            if (i4 < lim4) {
                int e = i4 * 4;
                if (e + 4 <= E) {
                    int4 d = dv[i4];
                    rr[k * 4 + 0] = (unsigned short)atomicAdd(&sm.p.h[d.x >> 7], 1);
                    rr[k * 4 + 1] = (unsigned short)atomicAdd(&sm.p.h[d.y >> 7], 1);
                    rr[k * 4 + 2] = (unsigned short)atomicAdd(&sm.p.h[d.z >> 7], 1);
                    rr[k * 4 + 3] = (unsigned short)atomicAdd(&sm.p.h[d.w >> 7], 1);
                } else {
#pragma unroll
                    for (int j = 0; j < 4; ++j) {
                        int e2 = e + j;
                        if (e2 < E)
                            rr[k * 4 + j] = (unsigned short)atomicAdd(&sm.p.h[dst[e2] >> 7], 1);
                    }
                }
            }
        }
        __syncthreads();

        // reserve global space per bucket
        for (int b = tid; b < NB; b += TPB)
            sm.p.startb[b] = atomicAdd(&cursor[b], sm.p.h[b]);

        // tile-local exclusive scan (wave 0)
        if (tid < 64) {
            int run = 0;
            for (int c = 0; c < NBMAX; c += 64) {
                int b = c + tid;
                int v = (b < NB) ? sm.p.h[b] : 0;
                int inc = v;
#pragma unroll
                for (int d = 1; d < 64; d <<= 1) {
                    int o = __shfl_up(inc, d);
                    if (tid >= d) inc += o;
                }
                if (b < NB) sm.p.lofs[b] = run + inc - v;
                run += __shfl(inc, 63);
            }
        }
        __syncthreads();

        // pass B: scatter into LDS-sorted tile (re-read src/dst, L2-warm)
#pragma unroll
        for (int k = 0; k < I4PT; ++k) {
            int i4 = base4 + k * TPB + tid;
            if (i4 < lim4) {
                int e = i4 * 4;
                if (e + 4 <= E) {
                    int4 d = dv[i4];
                    int4 s = sv[i4];
                    sm.p.sorted[sm.p.lofs[d.x >> 7] + (int)rr[k * 4 + 0]] =
                        ((unsigned)s.x << 7) | (unsigned)(d.x & 127);
                    sm.p.sorted[sm.p.lofs[d.y >> 7] + (int)rr[k * 4 + 1]] =
                        ((unsigned)s.y << 7) | (unsigned)(d.y & 127);
                    sm.p.sorted[sm.p.lofs[d.z >> 7] + (int)rr[k * 4 + 2]] =
                        ((unsigned)s.z << 7) | (unsigned)(d.z & 127);
                    sm.p.sorted[sm.p.lofs[d.w >> 7] + (int)rr[k * 4 + 3]] =
                        ((unsigned)s.w << 7) | (unsigned)(d.w & 127);
                } else {
#pragma unroll
                    for (int j = 0; j < 4; ++j) {
                        int e2 = e + j;
                        if (e2 < E) {
                            int d = dst[e2];
                            int s = src[e2];
                            sm.p.sorted[sm.p.lofs[d >> 7] + (int)rr[k * 4 + j]] =
                                ((unsigned)s << 7) | (unsigned)(d & 127);
                        }
                    }
                }
            }
        }
        __syncthreads();

        // flush: 16-lane groups -> dense coalesced lines
        int grp = tid >> 4, lane16 = tid & 15;
        int ngrp = TPB / 16;
        for (int b = grp; b < NB; b += ngrp) {
            int cnt = sm.p.h[b];
            int sb = sm.p.startb[b];
            int lim = MAXBE - sb;
            if (cnt > lim) cnt = lim;  // overflow guard
            int gb = b * MAXBE + sb;
            int lo = sm.p.lofs[b];
            for (int j = lane16; j < cnt; j += 16)
                spack[gb + j] = sm.p.sorted[lo + j];
        }
        __syncthreads();
    }
    grid.sync();

    // ---------------- phase A: node sort -> csr, wx, offn, degn ----------------
    for (int b = blockIdx.x; b < NB; b += gridDim.x) {
        if (tid < NPB) sm.a.c[tid] = 0;
        __syncthreads();
        int beg = b * MAXBE;
        int cnt = cursor[b];
        if (cnt > MAXBE) cnt = MAXBE;

        unsigned Ur[EPTH];
        int Rr[EPTH];
#pragma unroll
        for (int j = 0; j < EPTH; ++j) {
            int idx = j * TPB + tid;
            if (idx < cnt) {
                unsigned u = spack[beg + idx];
                Ur[j] = u;
                Rr[j] = atomicAdd(&sm.a.c[u & 127], 1);
            } else {
                Rr[j] = -1;
            }
        }
        __syncthreads();

        // exclusive scan of 128 degrees (wave 0)
        if (tid < 64) {
            int run = 0;
            for (int cb = 0; cb < NPB; cb += 64) {
                int v = sm.a.c[cb + tid];
                int inc = v;
#pragma unroll
                for (int d = 1; d < 64; d <<= 1) {
                    int o = __shfl_up(inc, d);
                    if (tid >= d) inc += o;
                }
                sm.a.lofs[cb + tid] = run + inc - v;
                run += __shfl(inc, 63);
            }
        }
        __syncthreads();

        if (tid < NPB) {
            int i = b * NPB + tid;
            if (i < N) {
                int dg = sm.a.c[tid];
                offn[i] = beg + sm.a.lofs[tid];
                degn[i] = dg;
                float dv = rsqrtf((float)(dg + 1));  // +1 self-loop
                float4 xs = reinterpret_cast<const float4*>(x)[i];
                reinterpret_cast<float4*>(wx)[i] =
                    make_float4(dv * xs.x, dv * xs.y, dv * xs.z, dv * xs.w);
            }
        }
        // scatter src into node-sorted csr (global)
#pragma unroll
        for (int j = 0; j < EPTH; ++j) {
            if (Rr[j] >= 0) {
                unsigned u = Ur[j];
                int loc = u & 127;
                csr[beg + sm.a.lofs[loc] + Rr[j]] = (int)(u >> 7);
            }
        }
        __syncthreads();
    }
    grid.sync();

    // ---------------- phase B: l1 -> wt ----------------
    if (tid < 64) sm.b.sW1[tid] = W1[tid];
    else if (tid < 80) sm.b.sb1[tid - 64] = b1[tid - 64];
    else if (tid < 112) sm.b.sW2[tid - 80] = W2[tid - 80];
    __syncthreads();
    {
        const float4* wxv = reinterpret_cast<const float4*>(wx);
        int sub = tid & 3;
        for (int b = blockIdx.x; b < NB; b += gridDim.x) {
            int beg = b * MAXBE;
            int cnt = cursor[b];
            if (cnt > MAXBE) cnt = MAXBE;
            int n4 = (cnt + 3) >> 2;
            const int4* cv = reinterpret_cast<const int4*>(csr + beg);
            for (int j = tid; j < n4; j += TPB)
                reinterpret_cast<int4*>(sm.b.lsrc)[sw4(j)] = cv[j];
            __syncthreads();
            int i = b * NPB + (tid >> 2);
            float a0 = 0.f, a1 = 0.f, a2 = 0.f, a3 = 0.f;
            int dg = 0;
            if (i < N) {
                dg = degn[i];
                int lo = offn[i] - beg;
                for (int k = sub; k < dg; k += 4) {
                    int s = sm.b.lsrc[sw(lo + k)];
                    float4 v = wxv[s];
                    a0 += v.x; a1 += v.y; a2 += v.z; a3 += v.w;
                }
            }
#pragma unroll
            for (int d = 1; d < 4; d <<= 1) {
                a0 += __shfl_xor(a0, d);
                a1 += __shfl_xor(a1, d);
                a2 += __shfl_xor(a2, d);
                a3 += __shfl_xor(a3, d);
            }
            if (sub == 0 && i < N) {
                float dv = rsqrtf((float)(dg + 1));
                float4 w4 = wxv[i];
                a0 = dv * (a0 + w4.x);
                a1 = dv * (a1 + w4.y);
                a2 = dv * (a2 + w4.z);
                a3 = dv * (a3 + w4.w);
                float t0 = 0.f, t1 = 0.f;
#pragma unroll
                for (int k = 0; k < 16; ++k) {
                    float h = fmaf(a0, sm.b.sW1[k],
                              fmaf(a1, sm.b.sW1[16 + k],
                              fmaf(a2, sm.b.sW1[32 + k],
                              fmaf(a3, sm.b.sW1[48 + k], sm.b.sb1[k]))));
                    h = fmaxf(h, 0.f);
                    t0 = fmaf(h, sm.b.sW2[2 * k + 0], t0);
                    t1 = fmaf(h, sm.b.sW2[2 * k + 1], t1);
                }
                reinterpret_cast<float2*>(wt)[i] = make_float2(dv * t0, dv * t1);
            }
            __syncthreads();
        }
    }
    grid.sync();

    // ---------------- phase C: l2 -> out ----------------
    {
        const float2* wtv = reinterpret_cast<const float2*>(wt);
        float b20 = b2[0], b21 = b2[1];
        int sub = tid & 3;
        for (int b = blockIdx.x; b < NB; b += gridDim.x) {
            int beg = b * MAXBE;
            int cnt = cursor[b];
            if (cnt > MAXBE) cnt = MAXBE;
            int n4 = (cnt + 3) >> 2;
            const int4* cv = reinterpret_cast<const int4*>(csr + beg);
            for (int j = tid; j < n4; j += TPB)
                reinterpret_cast<int4*>(sm.b.lsrc)[sw4(j)] = cv[j];
            __syncthreads();
            int i = b * NPB + (tid >> 2);
            float s0 = 0.f, s1 = 0.f;
            int dg = 0;
            if (i < N) {
                dg = degn[i];
                int lo = offn[i] - beg;
                for (int k = sub; k < dg; k += 4) {
                    int s = sm.b.lsrc[sw(lo + k)];
                    float2 v = wtv[s];
                    s0 += v.x; s1 += v.y;
                }
            }
#pragma unroll
            for (int d = 1; d < 4; d <<= 1) {
                s0 += __shfl_xor(s0, d);
                s1 += __shfl_xor(s1, d);
            }
            if (sub == 0 && i < N) {
                float dv = rsqrtf((float)(dg + 1));
                float2 w = wtv[i];
                reinterpret_cast<float2*>(out)[i] =
                    make_float2(dv * (s0 + w.x) + b20, dv * (s1 + w.y) + b21);
            }
            __syncthreads();
        }
    }
}

// ================= fallback path (R12, measured 234 us) =================

__global__ __launch_bounds__(TPB, 4) void k_part(const int* __restrict__ src,
                                                 const int* __restrict__ dst,
                                                 int E, int NB,
                                                 int* __restrict__ cursor,
                                                 unsigned int* __restrict__ spack) {
    __shared__ int h[NBMAX];
    __shared__ int lofs[NBMAX];
    __shared__ int startb[NBMAX];
    __shared__ unsigned int sorted[FTILE];
    int tid = threadIdx.x;
    int t = blockIdx.x;
    for (int j = tid; j < NB; j += TPB) h[j] = 0;
    __syncthreads();
    const int4* dv = reinterpret_cast<const int4*>(dst);
    const int4* sv = reinterpret_cast<const int4*>(src);
    int base4 = t * (FTILE / 4);
    int4 dreg[FEPT / 4];
    unsigned short rr[FEPT];
#pragma unroll
    for (int k = 0; k < FEPT / 4; ++k) {
        int i4 = base4 + k * TPB + tid;
        int e = i4 * 4;
        if (e + 4 <= E) {
            int4 d = dv[i4];
            dreg[k] = d;
            rr[k * 4 + 0] = (unsigned short)atomicAdd(&h[d.x >> 7], 1);
            rr[k * 4 + 1] = (unsigned short)atomicAdd(&h[d.y >> 7], 1);
            rr[k * 4 + 2] = (unsigned short)atomicAdd(&h[d.z >> 7], 1);
            rr[k * 4 + 3] = (unsigned short)atomicAdd(&h[d.w >> 7], 1);
        } else {
            int dd[4] = {-1, -1, -1, -1};
#pragma unroll
            for (int j = 0; j < 4; ++j) {
                int e2 = e + j;
                if (e2 < E) {
                    dd[j] = dst[e2];
                    rr[k * 4 + j] = (unsigned short)atomicAdd(&h[dd[j] >> 7], 1);
                }
            }
            dreg[k] = make_int4(dd[0], dd[1], dd[2], dd[3]);
        }
    }
    __syncthreads();
    for (int b = tid; b < NB; b += TPB)
        startb[b] = atomicAdd(&cursor[b], h[b]);
    if (tid < 64) {
        int run = 0;
        for (int c = 0; c < NBMAX; c += 64) {
            int b = c + tid;
            int v = (b < NB) ? h[b] : 0;
            int inc = v;
#pragma unroll
            for (int d = 1; d < 64; d <<= 1) {
                int o = __shfl_up(inc, d);
                if (tid >= d) inc += o;
            }
            if (b < NB) lofs[b] = run + inc - v;
            run += __shfl(inc, 63);
        }
    }
    __syncthreads();
#pragma unroll
    for (int k = 0; k < FEPT / 4; ++k) {
        int i4 = base4 + k * TPB + tid;
        int e = i4 * 4;
        if (e + 4 <= E) {
            int4 s = sv[i4];
            int4 d = dreg[k];
            sorted[lofs[d.x >> 7] + (int)rr[k * 4 + 0]] = ((unsigned)s.x << 7) | (unsigned)(d.x & 127);
            sorted[lofs[d.y >> 7] + (int)rr[k * 4 + 1]] = ((unsigned)s.y << 7) | (unsigned)(d.y & 127);
            sorted[lofs[d.z >> 7] + (int)rr[k * 4 + 2]] = ((unsigned)s.z << 7) | (unsigned)(d.z & 127);
            sorted[lofs[d.w >> 7] + (int)rr[k * 4 + 3]] = ((unsigned)s.w << 7) | (unsigned)(d.w & 127);
        } else {
            int dd[4] = {dreg[k].x, dreg[k].y, dreg[k].z, dreg[k].w};
#pragma unroll
            for (int j = 0; j < 4; ++j) {
                int e2 = e + j;
                if (e2 < E && dd[j] >= 0) {
                    int s = src[e2];
                    sorted[lofs[dd[j] >> 7] + (int)rr[k * 4 + j]] =
                        ((unsigned)s << 7) | (unsigned)(dd[j] & 127);
                }
            }
        }
    }
    __syncthreads();
    int grp = tid >> 4, lane16 = tid & 15;
    int ngrp = TPB / 16;
    for (int b = grp; b < NB; b += ngrp) {
        int cnt = h[b];
        int sb = startb[b];
        int lim = MAXBE - sb;
        if (cnt > lim) cnt = lim;
        int gb = b * MAXBE + sb;
        int lo = lofs[b];
        for (int j = lane16; j < cnt; j += 16)
            spack[gb + j] = sorted[lo + j];
    }
}

__global__ __launch_bounds__(TPB, 8) void k_node1(const unsigned int* __restrict__ spack,
                                                  const int* __restrict__ cursor,
                                                  const float* __restrict__ x, int N,
                                                  float* __restrict__ wx, int* __restrict__ offn,
                                                  int* __restrict__ degn, int* __restrict__ csr) {
    __shared__ int c[NPB];
    __shared__ int lofs[NPB];
    __shared__ unsigned short r2[MAXBE];
    int tid = threadIdx.x;
    int b = blockIdx.x;
    if (tid < NPB) c[tid] = 0;
    __syncthreads();
    int beg = b * MAXBE;
    int cnt = cursor[b];
    if (cnt > MAXBE) cnt = MAXBE;
    int end = beg + cnt;
    for (int e = beg + tid; e < end; e += TPB) {
        unsigned u = spack[e];
        r2[e - beg] = (unsigned short)atomicAdd(&c[u & 127], 1);
    }
    __syncthreads();
    if (tid < NPB) lofs[tid] = c[tid];
    __syncthreads();
    for (int off = 1; off < NPB; off <<= 1) {
        int add = (tid < NPB && tid >= off) ? lofs[tid - off] : 0;
        __syncthreads();
        if (tid < NPB) lofs[tid] += add;
        __syncthreads();
    }
    if (tid < NPB) {
        int i = b * NPB + tid;
        if (i < N) {
            int dg = c[tid];
            int excl = lofs[tid] - dg;
            offn[i] = beg + excl;
            degn[i] = dg;
            float dv = rsqrtf((float)(dg + 1));
            float4 xs = reinterpret_cast<const float4*>(x)[i];
            reinterpret_cast<float4*>(wx)[i] =
                make_float4(dv * xs.x, dv * xs.y, dv * xs.z, dv * xs.w);
        }
    }
    __syncthreads();
    for (int e = beg + tid; e < end; e += TPB) {
        unsigned u = spack[e];
        int loc = u & 127;
        int pos = beg + (lofs[loc] - c[loc]) + (int)r2[e - beg];
        csr[pos] = (int)(u >> 7);
    }
}

__global__ __launch_bounds__(TPB, 8) void k_l1(const int* __restrict__ csr,
                                               const int* __restrict__ cursor,
                                               const int* __restrict__ offn,
                                               const int* __restrict__ degn,
                                               const float* __restrict__ wx,
                                               const float* __restrict__ W1,
                                               const float* __restrict__ b1,
                                               const float* __restrict__ W2,
                                               float* __restrict__ wt, int N) {
    __shared__ int lsrc[MAXBE];
    __shared__ float sW1[64], sb1[16], sW2[32];
    int tid = threadIdx.x;
    int b = blockIdx.x;
    if (tid < 64) sW1[tid] = W1[tid];
    else if (tid < 80) sb1[tid - 64] = b1[tid - 64];
    else if (tid < 112) sW2[tid - 80] = W2[tid - 80];
    int beg = b * MAXBE;
    int cnt = cursor[b];
    if (cnt > MAXBE) cnt = MAXBE;
    int n4 = (cnt + 3) >> 2;
    const int4* cv = reinterpret_cast<const int4*>(csr + beg);
    for (int j = tid; j < n4; j += TPB)
        reinterpret_cast<int4*>(lsrc)[sw4(j)] = cv[j];
    __syncthreads();
    int i = b * NPB + (tid >> 2);
    int sub = tid & 3;
    const float4* wxv = reinterpret_cast<const float4*>(wx);
    float a0 = 0.f, a1 = 0.f, a2 = 0.f, a3 = 0.f;
    int dg = 0, lo = 0;
    if (i < N) {
        dg = degn[i];
        lo = offn[i] - beg;
        for (int k = sub; k < dg; k += 4) {
            int s = lsrc[sw(lo + k)];
            float4 v = wxv[s];
            a0 += v.x; a1 += v.y; a2 += v.z; a3 += v.w;
        }
    }
#pragma unroll
    for (int d = 1; d < 4; d <<= 1) {
        a0 += __shfl_xor(a0, d);
        a1 += __shfl_xor(a1, d);
        a2 += __shfl_xor(a2, d);
        a3 += __shfl_xor(a3, d);
    }
    if (sub == 0 && i < N) {
        float dv = rsqrtf((float)(dg + 1));
        float4 w4 = wxv[i];
        a0 = dv * (a0 + w4.x);
        a1 = dv * (a1 + w4.y);
        a2 = dv * (a2 + w4.z);
        a3 = dv * (a3 + w4.w);
        float t0 = 0.f, t1 = 0.f;
#pragma unroll
        for (int k = 0; k < 16; ++k) {
            float h = fmaf(a0, sW1[k],
                      fmaf(a1, sW1[16 + k],
                      fmaf(a2, sW1[32 + k],
                      fmaf(a3, sW1[48 + k], sb1[k]))));
            h = fmaxf(h, 0.f);
            t0 = fmaf(h, sW2[2 * k + 0], t0);
            t1 = fmaf(h, sW2[2 * k + 1], t1);
        }
        reinterpret_cast<float2*>(wt)[i] = make_float2(dv * t0, dv * t1);
    }
}

__global__ __launch_bounds__(TPB, 8) void k_l2(const int* __restrict__ csr,
                                               const int* __restrict__ cursor,
                                               const int* __restrict__ offn,
                                               const int* __restrict__ degn,
                                               const float* __restrict__ wt,
                                               const float* __restrict__ b2,
                                               float* __restrict__ out, int N) {
    __shared__ int lsrc[MAXBE];
    int tid = threadIdx.x;
    int b = blockIdx.x;
    int beg = b * MAXBE;
    int cnt = cursor[b];
    if (cnt > MAXBE) cnt = MAXBE;
    int n4 = (cnt + 3) >> 2;
    const int4* cv = reinterpret_cast<const int4*>(csr + beg);
    for (int j = tid; j < n4; j += TPB)
        reinterpret_cast<int4*>(lsrc)[sw4(j)] = cv[j];
    __syncthreads();
    int i = b * NPB + (tid >> 2);
    int sub = tid & 3;
    const float2* wtv = reinterpret_cast<const float2*>(wt);
    float s0 = 0.f, s1 = 0.f;
    int dg = 0, lo = 0;
    if (i < N) {
        dg = degn[i];
        lo = offn[i] - beg;
        for (int k = sub; k < dg; k += 4) {
            int s = lsrc[sw(lo + k)];
            float2 v = wtv[s];
            s0 += v.x; s1 += v.y;
        }
    }
#pragma unroll
    for (int d = 1; d < 4; d <<= 1) {
        s0 += __shfl_xor(s0, d);
        s1 += __shfl_xor(s1, d);
    }
    if (sub == 0 && i < N) {
        float dv = rsqrtf((float)(dg + 1));
        float2 w = wtv[i];
        out[2 * i + 0] = dv * (s0 + w.x) + b2[0];
        out[2 * i + 1] = dv * (s1 + w.y) + b2[1];
    }
}

extern "C" void kernel_launch(void* const* d_in, const int* in_sizes, int n_in,
                              void* d_out, int out_size, void* d_ws, size_t ws_size,
                              hipStream_t stream) {
    const float* x  = (const float*)d_in[0];
    const int*   ei = (const int*)d_in[1];
    const float* W1 = (const float*)d_in[2];
    const float* b1 = (const float*)d_in[3];
    const float* W2 = (const float*)d_in[4];
    const float* b2 = (const float*)d_in[5];
    float* out = (float*)d_out;

    int N = in_sizes[0] / 4;
    int E = in_sizes[1] / 2;
    const int* src = ei;
    const int* dst = ei + E;

    const int NB = (N + NPB - 1) / NPB;     // 782
    const int FT = (E + FTILE - 1) / FTILE; // 391 (fallback)

    char* p = (char*)d_ws;
    auto carve = [&](size_t bytes) {
        char* r = p;
        p += (bytes + 15) & ~(size_t)15;
        return (void*)r;
    };
    int* cursor = (int*)carve((size_t)NBMAX * 4);
    unsigned int* spack = (unsigned int*)carve((size_t)NB * MAXBE * 4);
    int*   csr  = (int*)carve((size_t)NB * MAXBE * 4);
    float* wx   = (float*)carve((size_t)N * 4 * 4);
    float* wt   = (float*)carve((size_t)N * 2 * 4);
    int*   offn = (int*)carve((size_t)N * 4);
    int*   degn = (int*)carve((size_t)N * 4);

    hipMemsetAsync(cursor, 0, (size_t)NBMAX * 4, stream);

    void* args[] = {(void*)&src, (void*)&dst, (void*)&E, (void*)&cursor, (void*)&spack,
                    (void*)&x, (void*)&W1, (void*)&b1, (void*)&W2, (void*)&b2,
                    (void*)&wx, (void*)&wt, (void*)&offn, (void*)&degn, (void*)&csr,
                    (void*)&out, (void*)&N};
    hipError_t err = hipLaunchCooperativeKernel((const void*)k_uni, dim3(GRID), dim3(TPB),
                                                args, 0, stream);
    if (err != hipSuccess) {
        (void)hipGetLastError();  // clear sticky error
        hipMemsetAsync(cursor, 0, (size_t)NBMAX * 4, stream);
        k_part<<<FT, TPB, 0, stream>>>(src, dst, E, NB, cursor, spack);
        k_node1<<<NB, TPB, 0, stream>>>(spack, cursor, x, N, wx, offn, degn, csr);
        k_l1<<<NB, TPB, 0, stream>>>(csr, cursor, offn, degn, wx, W1, b1, W2, wt, N);
        k_l2<<<NB, TPB, 0, stream>>>(csr, cursor, offn, degn, wt, b2, out, N);
    }
}

// Round 15
// 231.006 us; speedup vs baseline: 1.6142x; 1.6142x over previous
//
#include <hip/hip_runtime.h>

// N=100000, E=6400000. Buckets of 128 nodes -> NB=782. Tiles of 16384 edges -> T=391.
constexpr int TILE  = 16384;  // edges per tile
constexpr int TPBP  = 1024;   // threads for k_part (2 blocks/CU at 76KB LDS -> 32 waves/CU)
constexpr int TPB   = 512;    // threads for k_node1 / k_l1 / k_l2
constexpr int EPTP  = TILE / TPBP;  // 16 edges per thread in k_part
constexpr int NPB   = 128;    // nodes per bucket
constexpr int NBMAX = 1024;   // LDS sizing bound for NB
constexpr int MAXBE = 10240;  // max edges per bucket (mean ~8184, +22 sigma)

__device__ __forceinline__ int sw(int j)  { return j ^ (((j >> 7) & 7) << 2); }  // word swizzle
__device__ __forceinline__ int sw4(int j) { return j ^ ((j >> 5) & 7); }         // int4 swizzle

// ---- fused hist + rank(regs) + reserve + LDS-sort + 16-lane flush ----
// TPBP=1024: 32 waves/CU for latency hiding; rank-only in regs (VGPR <= 64).
__global__ __launch_bounds__(TPBP, 8) void k_part(const int* __restrict__ src,
                                                  const int* __restrict__ dst,
                                                  int E, int NB,
                                                  int* __restrict__ cursor,
                                                  unsigned int* __restrict__ spack) {
    __shared__ int h[NBMAX];
    __shared__ int lofs[NBMAX];
    __shared__ int startb[NBMAX];
    __shared__ unsigned int sorted[TILE];  // 64 KB

    int tid = threadIdx.x;
    int t = blockIdx.x;
    for (int j = tid; j < NBMAX; j += TPBP) h[j] = 0;
    __syncthreads();

    const int4* dv = reinterpret_cast<const int4*>(dst);
    const int4* sv = reinterpret_cast<const int4*>(src);
    int base4 = t * (TILE / 4);

    unsigned short rr[EPTP];  // per-edge rank within (tile,bucket)

    // pass A: LDS histogram; rank kept in registers; dst re-read in pass B (L2-warm)
#pragma unroll
    for (int k = 0; k < EPTP / 4; ++k) {  // 4 iters
        int i4 = base4 + k * TPBP + tid;
        int e = i4 * 4;
        if (e + 4 <= E) {
            int4 d = dv[i4];
            rr[k * 4 + 0] = (unsigned short)atomicAdd(&h[d.x >> 7], 1);
            rr[k * 4 + 1] = (unsigned short)atomicAdd(&h[d.y >> 7], 1);
            rr[k * 4 + 2] = (unsigned short)atomicAdd(&h[d.z >> 7], 1);
            rr[k * 4 + 3] = (unsigned short)atomicAdd(&h[d.w >> 7], 1);
        } else {
#pragma unroll
            for (int j = 0; j < 4; ++j) {
                int e2 = e + j;
                if (e2 < E)
                    rr[k * 4 + j] = (unsigned short)atomicAdd(&h[dst[e2] >> 7], 1);
            }
        }
    }
    __syncthreads();

    // reserve global space per bucket
    for (int b = tid; b < NB; b += TPBP)
        startb[b] = atomicAdd(&cursor[b], h[b]);

    // tile-local exclusive scan of h -> lofs (wave 0)
    if (tid < 64) {
        int run = 0;
        for (int c = 0; c < NBMAX; c += 64) {
            int b = c + tid;
            int v = (b < NB) ? h[b] : 0;
            int inc = v;
#pragma unroll
            for (int d = 1; d < 64; d <<= 1) {
                int o = __shfl_up(inc, d);
                if (tid >= d) inc += o;
            }
            if (b < NB) lofs[b] = run + inc - v;
            run += __shfl(inc, 63);
        }
    }
    __syncthreads();

    // pass B: re-read src/dst (L2-warm), scatter packed edges into LDS-sorted tile
#pragma unroll
    for (int k = 0; k < EPTP / 4; ++k) {
        int i4 = base4 + k * TPBP + tid;
        int e = i4 * 4;
        if (e + 4 <= E) {
            int4 d = dv[i4];
            int4 s = sv[i4];
            sorted[lofs[d.x >> 7] + (int)rr[k * 4 + 0]] = ((unsigned)s.x << 7) | (unsigned)(d.x & 127);
            sorted[lofs[d.y >> 7] + (int)rr[k * 4 + 1]] = ((unsigned)s.y << 7) | (unsigned)(d.y & 127);
            sorted[lofs[d.z >> 7] + (int)rr[k * 4 + 2]] = ((unsigned)s.z << 7) | (unsigned)(d.z & 127);
            sorted[lofs[d.w >> 7] + (int)rr[k * 4 + 3]] = ((unsigned)s.w << 7) | (unsigned)(d.w & 127);
        } else {
#pragma unroll
            for (int j = 0; j < 4; ++j) {
                int e2 = e + j;
                if (e2 < E) {
                    int d = dst[e2];
                    int s = src[e2];
                    sorted[lofs[d >> 7] + (int)rr[k * 4 + j]] =
                        ((unsigned)s << 7) | (unsigned)(d & 127);
                }
            }
        }
    }
    __syncthreads();

    // flush: 16-lane sub-group per bucket -> dense coalesced lines
    int grp = tid >> 4, lane16 = tid & 15;
    int ngrp = TPBP / 16;
    for (int b = grp; b < NB; b += ngrp) {
        int cnt = h[b];
        int sb = startb[b];
        int lim = MAXBE - sb;
        if (cnt > lim) cnt = lim;  // overflow guard (statistically unreachable)
        int gb = b * MAXBE + sb;
        int lo = lofs[b];
        for (int j = lane16; j < cnt; j += 16)
            spack[gb + j] = sorted[lo + j];
    }
}

// ---- per-bucket node sort -> CSR; degrees, wx ----
__global__ __launch_bounds__(TPB, 8) void k_node1(const unsigned int* __restrict__ spack,
                                                  const int* __restrict__ cursor,
                                                  const float* __restrict__ x, int N,
                                                  float* __restrict__ wx, int* __restrict__ offn,
                                                  int* __restrict__ degn, int* __restrict__ csr) {
    __shared__ int c[NPB];
    __shared__ int lofs[NPB];
    __shared__ unsigned short r2[MAXBE];
    int tid = threadIdx.x;  // 512
    int b = blockIdx.x;
    if (tid < NPB) c[tid] = 0;
    __syncthreads();
    int beg = b * MAXBE;
    int cnt = cursor[b];
    if (cnt > MAXBE) cnt = MAXBE;
    int end = beg + cnt;
    for (int e = beg + tid; e < end; e += TPB) {
        unsigned u = spack[e];
        r2[e - beg] = (unsigned short)atomicAdd(&c[u & 127], 1);
    }
    __syncthreads();
    if (tid < NPB) lofs[tid] = c[tid];
    __syncthreads();
    for (int off = 1; off < NPB; off <<= 1) {
        int add = (tid < NPB && tid >= off) ? lofs[tid - off] : 0;
        __syncthreads();
        if (tid < NPB) lofs[tid] += add;
        __syncthreads();
    }
    if (tid < NPB) {
        int i = b * NPB + tid;
        if (i < N) {
            int dg = c[tid];
            int excl = lofs[tid] - dg;
            offn[i] = beg + excl;
            degn[i] = dg;
            float dv = rsqrtf((float)(dg + 1));
            float4 xs = reinterpret_cast<const float4*>(x)[i];
            reinterpret_cast<float4*>(wx)[i] =
                make_float4(dv * xs.x, dv * xs.y, dv * xs.z, dv * xs.w);
        }
    }
    __syncthreads();
    for (int e = beg + tid; e < end; e += TPB) {
        unsigned u = spack[e];
        int loc = u & 127;
        int pos = beg + (lofs[loc] - c[loc]) + (int)r2[e - beg];
        csr[pos] = (int)(u >> 7);
    }
}

// ---- block-per-bucket, 4 lanes per node: LDS-staged csr gather + MLP -> wt ----
__global__ __launch_bounds__(TPB, 8) void k_l1(const int* __restrict__ csr,
                                               const int* __restrict__ cursor,
                                               const int* __restrict__ offn,
                                               const int* __restrict__ degn,
                                               const float* __restrict__ wx,
                                               const float* __restrict__ W1,
                                               const float* __restrict__ b1,
                                               const float* __restrict__ W2,
                                               float* __restrict__ wt, int N) {
    __shared__ int lsrc[MAXBE];  // 40 KB, xor-swizzled
    __shared__ float sW1[64], sb1[16], sW2[32];
    int tid = threadIdx.x;
    int b = blockIdx.x;
    if (tid < 64) sW1[tid] = W1[tid];
    else if (tid < 80) sb1[tid - 64] = b1[tid - 64];
    else if (tid < 112) sW2[tid - 80] = W2[tid - 80];
    int beg = b * MAXBE;
    int cnt = cursor[b];
    if (cnt > MAXBE) cnt = MAXBE;
    int n4 = (cnt + 3) >> 2;
    const int4* cv = reinterpret_cast<const int4*>(csr + beg);
    for (int j = tid; j < n4; j += TPB)
        reinterpret_cast<int4*>(lsrc)[sw4(j)] = cv[j];
    __syncthreads();
    int i = b * NPB + (tid >> 2);
    int sub = tid & 3;
    const float4* wxv = reinterpret_cast<const float4*>(wx);
    float a0 = 0.f, a1 = 0.f, a2 = 0.f, a3 = 0.f;
    int dg = 0, lo = 0;
    if (i < N) {
        dg = degn[i];
        lo = offn[i] - beg;
        for (int k = sub; k < dg; k += 4) {
            int s = lsrc[sw(lo + k)];
            float4 v = wxv[s];
            a0 += v.x; a1 += v.y; a2 += v.z; a3 += v.w;
        }
    }
#pragma unroll
    for (int d = 1; d < 4; d <<= 1) {
        a0 += __shfl_xor(a0, d);
        a1 += __shfl_xor(a1, d);
        a2 += __shfl_xor(a2, d);
        a3 += __shfl_xor(a3, d);
    }
    if (sub == 0 && i < N) {
        float dv = rsqrtf((float)(dg + 1));
        float4 w4 = wxv[i];
        a0 = dv * (a0 + w4.x);
        a1 = dv * (a1 + w4.y);
        a2 = dv * (a2 + w4.z);
        a3 = dv * (a3 + w4.w);
        float t0 = 0.f, t1 = 0.f;
#pragma unroll
        for (int k = 0; k < 16; ++k) {
            float h = fmaf(a0, sW1[k],
                      fmaf(a1, sW1[16 + k],
                      fmaf(a2, sW1[32 + k],
                      fmaf(a3, sW1[48 + k], sb1[k]))));
            h = fmaxf(h, 0.f);
            t0 = fmaf(h, sW2[2 * k + 0], t0);
            t1 = fmaf(h, sW2[2 * k + 1], t1);
        }
        reinterpret_cast<float2*>(wt)[i] = make_float2(dv * t0, dv * t1);
    }
}

// ---- block-per-bucket, 4 lanes per node: LDS-staged csr gather wt -> out ----
__global__ __launch_bounds__(TPB, 8) void k_l2(const int* __restrict__ csr,
                                               const int* __restrict__ cursor,
                                               const int* __restrict__ offn,
                                               const int* __restrict__ degn,
                                               const float* __restrict__ wt,
                                               const float* __restrict__ b2,
                                               float* __restrict__ out, int N) {
    __shared__ int lsrc[MAXBE];
    int tid = threadIdx.x;
    int b = blockIdx.x;
    int beg = b * MAXBE;
    int cnt = cursor[b];
    if (cnt > MAXBE) cnt = MAXBE;
    int n4 = (cnt + 3) >> 2;
    const int4* cv = reinterpret_cast<const int4*>(csr + beg);
    for (int j = tid; j < n4; j += TPB)
        reinterpret_cast<int4*>(lsrc)[sw4(j)] = cv[j];
    __syncthreads();
    int i = b * NPB + (tid >> 2);
    int sub = tid & 3;
    const float2* wtv = reinterpret_cast<const float2*>(wt);
    float s0 = 0.f, s1 = 0.f;
    int dg = 0, lo = 0;
    if (i < N) {
        dg = degn[i];
        lo = offn[i] - beg;
        for (int k = sub; k < dg; k += 4) {
            int s = lsrc[sw(lo + k)];
            float2 v = wtv[s];
            s0 += v.x; s1 += v.y;
        }
    }
#pragma unroll
    for (int d = 1; d < 4; d <<= 1) {
        s0 += __shfl_xor(s0, d);
        s1 += __shfl_xor(s1, d);
    }
    if (sub == 0 && i < N) {
        float dv = rsqrtf((float)(dg + 1));
        float2 w = wtv[i];
        out[2 * i + 0] = dv * (s0 + w.x) + b2[0];
        out[2 * i + 1] = dv * (s1 + w.y) + b2[1];
    }
}

extern "C" void kernel_launch(void* const* d_in, const int* in_sizes, int n_in,
                              void* d_out, int out_size, void* d_ws, size_t ws_size,
                              hipStream_t stream) {
    const float* x  = (const float*)d_in[0];
    const int*   ei = (const int*)d_in[1];
    const float* W1 = (const float*)d_in[2];
    const float* b1 = (const float*)d_in[3];
    const float* W2 = (const float*)d_in[4];
    const float* b2 = (const float*)d_in[5];
    float* out = (float*)d_out;

    const int N = in_sizes[0] / 4;
    const int E = in_sizes[1] / 2;
    const int* src = ei;
    const int* dst = ei + E;

    const int NB = (N + NPB - 1) / NPB;   // 782
    const int T  = (E + TILE - 1) / TILE; // 391

    char* p = (char*)d_ws;
    auto carve = [&](size_t bytes) {
        char* r = p;
        p += (bytes + 15) & ~(size_t)15;
        return (void*)r;
    };
    int* cursor = (int*)carve((size_t)NBMAX * 4);
    unsigned int* spack = (unsigned int*)carve((size_t)NB * MAXBE * 4);  // 32.0 MB
    int*   csr  = (int*)carve((size_t)NB * MAXBE * 4);                   // 32.0 MB
    float* wx   = (float*)carve((size_t)N * 4 * 4);
    float* wt   = (float*)carve((size_t)N * 2 * 4);
    int*   offn = (int*)carve((size_t)N * 4);
    int*   degn = (int*)carve((size_t)N * 4);

    hipMemsetAsync(cursor, 0, (size_t)NBMAX * 4, stream);
    k_part<<<T, TPBP, 0, stream>>>(src, dst, E, NB, cursor, spack);
    k_node1<<<NB, TPB, 0, stream>>>(spack, cursor, x, N, wx, offn, degn, csr);
    k_l1<<<NB, TPB, 0, stream>>>(csr, cursor, offn, degn, wx, W1, b1, W2, wt, N);
    k_l2<<<NB, TPB, 0, stream>>>(csr, cursor, offn, degn, wt, b2, out, N);
}